// Round 1
// baseline (240.840 us; speedup 1.0000x reference)
//
#include <hip/hip_runtime.h>

// LSTM B=4096, S=512, INPUT=1, HIDDEN=20 + linear head.
// R4 (from R3's 3-chains/wave fp16-dot2 mapping):
//  - __launch_bounds__(64,2): grid is 1366 single-wave blocks -> never more
//    than 2 waves/SIMD resident, so the (64,4) 128-VGPR cap only forced the
//    allocator to shuffle the ~75-reg live set (40 w2 + 10 wl2 + pw + accs)
//    through AGPRs/remat.  Give it 256 VGPRs.
//  - Fused-reciprocal activations: 5 exp2 + 2 rcp per step (was 5+5).
//      c' = (c*(1+I)(1+G) + (1-G)(1+F)) * rcp((1+F)(1+I)(1+G))
//      h  = (1-C) * rcp((1+O)(1+C)),  C = exp2(-2*log2e*c')
//    exactly equivalent algebra (E=exp(-z) forms); c clamped at -34 to keep
//    the single new Inf/Inf path unreachable.
//  - Each gate dot split into two 5-deep dot2 chains + add: shortens the
//    serial LDS->gates dependence by ~5 dot2 latencies.

#define BATCH 4096
#define SLEN  512
#define H     20
#define CHUNK 16
#define LOG2E 1.44269504088896340736f
#define GSTRIDE 200   // words per group LDS region (16 rows * 12 + 8 pad)
#define RSTRIDE 12    // words per h row (10 half2 used + 2 pad)

typedef _Float16 h2 __attribute__((ext_vector_type(2)));

__device__ __forceinline__ float fexp2(float x) { return __builtin_amdgcn_exp2f(x); }
__device__ __forceinline__ float frcp(float x)  { return __builtin_amdgcn_rcpf(x); }
__device__ __forceinline__ h2 bch2(unsigned int u) { return __builtin_bit_cast(h2, u); }

__global__ __launch_bounds__(64, 2) void lstm_fused(
    const float* __restrict__ x,      // [B, S, 1]
    const float* __restrict__ W_ih,   // [80, 1]
    const float* __restrict__ W_hh,   // [80, 20]
    const float* __restrict__ b_ih,   // [80]
    const float* __restrict__ b_hh,   // [80]
    const float* __restrict__ W_lin,  // [1, 20]
    const float* __restrict__ b_lin,  // [1]
    float* __restrict__ out)          // [B, S, 1]
{
    __shared__ __align__(16) unsigned int hw[4 * GSTRIDE];  // h ring, fp16
    __shared__ float xbuf[4][CHUNK];
    _Float16* hh = (_Float16*)hw;

    const int lane = threadIdx.x;           // 0..63
    int grp = lane / H;                     // 0..3 (3 = dummy group)
    const int j = lane - grp * H;           // 0..19 (0..3 for dummy)
    const long b = (long)blockIdx.x * 3 + grp;
    const bool valid = (grp < 3) && (b < BATCH);
    const long bc = valid ? b : 0;

    const float s1 = -LOG2E;          // sigmoid pre-scale
    const float s2 = -2.0f * LOG2E;   // tanh pre-scale

    // ---- per-lane weights: 4 gate rows x 10 half2 (40 VGPRs), pre-scaled ----
    h2 w2[4][10];
    float bb[4], xw[4];
#pragma unroll
    for (int g = 0; g < 4; ++g) {
        const int row = g * H + j;
        const float sc = (g == 2) ? s2 : s1;   // torch gate order i,f,g,o
#pragma unroll
        for (int k = 0; k < 10; ++k) {
            h2 t;
            t.x = (_Float16)(sc * W_hh[row * H + 2 * k]);
            t.y = (_Float16)(sc * W_hh[row * H + 2 * k + 1]);
            w2[g][k] = t;
        }
        bb[g] = sc * (b_ih[row] + b_hh[row]);
        xw[g] = sc * W_ih[row];
    }
    h2 wl2[10];
#pragma unroll
    for (int k = 0; k < 10; ++k) {
        h2 t;
        t.x = (_Float16)W_lin[2 * k];
        t.y = (_Float16)W_lin[2 * k + 1];
        wl2[k] = t;
    }
    const float blin = b_lin[0];

    const float* xb = x + bc * SLEN;
    float*       ob = out + bc * SLEN;

    const int gbase = grp * GSTRIDE;
    // h(-1) = 0 in ring row CHUNK-1
    hh[2 * (gbase + (CHUNK - 1) * RSTRIDE) + j] = (_Float16)0.0f;
    float c = 0.0f;

#pragma unroll 1
    for (int T = 0; T < SLEN; T += CHUNK) {
        if (j < CHUNK) xbuf[grp][j] = xb[T + j];   // coalesced x chunk -> LDS

#pragma unroll
        for (int i = 0; i < CHUNK; ++i) {
            const int rp = (i + CHUNK - 1) & (CHUNK - 1);
            const int base = gbase + rp * RSTRIDE;
            const float xt = xbuf[grp][i];          // group broadcast (2-way: free)
            // h(t-1) row: 20 fp16 = words 0..9 -> b128 + b128 + b64
            const uint4 A = *(const uint4*)&hw[base];
            const uint4 B = *(const uint4*)&hw[base + 4];
            const uint2 C2 = *(const uint2*)&hw[base + 8];
            const unsigned int pw[10] = {A.x, A.y, A.z, A.w,
                                         B.x, B.y, B.z, B.w, C2.x, C2.y};
            float a[4], a2[4];
#pragma unroll
            for (int g = 0; g < 4; ++g) a[g] = fmaf(xt, xw[g], bb[g]);
            // two 5-deep chains per gate (halves serial dot latency)
#pragma unroll
            for (int k = 0; k < 5; ++k) {
#pragma unroll
                for (int g = 0; g < 4; ++g)
                    a[g] = __builtin_amdgcn_fdot2(bch2(pw[k]), w2[g][k], a[g], false);
            }
#pragma unroll
            for (int g = 0; g < 4; ++g)
                a2[g] = __builtin_amdgcn_fdot2(bch2(pw[5]), w2[g][5], 0.0f, false);
#pragma unroll
            for (int k = 6; k < 10; ++k) {
#pragma unroll
                for (int g = 0; g < 4; ++g)
                    a2[g] = __builtin_amdgcn_fdot2(bch2(pw[k]), w2[g][k], a2[g], false);
            }
#pragma unroll
            for (int g = 0; g < 4; ++g) a[g] += a2[g];

            // ---- fused-reciprocal activations: 5 exp2 + 2 rcp ----
            // E = exp(-z) forms (accumulators are pre-scaled by s1/s2):
            //   i = 1/(1+I), f = 1/(1+F), g = (1-G)/(1+G), o = 1/(1+O)
            const float eI = fexp2(a[0]);
            const float eF = fexp2(a[1]);
            const float eG = fexp2(a[2]);
            const float eO = fexp2(a[3]);
            const float pI = 1.0f + eI;
            const float pF = 1.0f + eF;
            const float pG = 1.0f + eG;
            const float pO = 1.0f + eO;
            const float mG = 1.0f - eG;
            const float P   = pI * pG;
            const float den = pF * P;
            const float num = fmaf(c, P, mG * pF);
            c = num * frcp(den);          // c' = f*c + i*g, one rcp
            c = fmaxf(c, -34.0f);         // guard exp2 overflow (no-op in practice)
            const float eC = fexp2(s2 * c);
            const float pC = 1.0f + eC;
            const float mC = 1.0f - eC;
            const float hval = mC * frcp(pO * pC);   // o * tanh(c'), one rcp
            hh[2 * (gbase + i * RSTRIDE) + j] = (_Float16)hval;  // ds_write_b16
        }

        // ---- deferred head: lanes j<16 reduce one stored row each ----
        if (j < CHUNK) {
            const int rb = gbase + j * RSTRIDE;
            const uint4 A = *(const uint4*)&hw[rb];
            const uint4 B = *(const uint4*)&hw[rb + 4];
            const uint2 C2 = *(const uint2*)&hw[rb + 8];
            const unsigned int pw[10] = {A.x, A.y, A.z, A.w,
                                         B.x, B.y, B.z, B.w, C2.x, C2.y};
            float y = blin;
#pragma unroll
            for (int k = 0; k < 10; ++k)
                y = __builtin_amdgcn_fdot2(bch2(pw[k]), wl2[k], y, false);
            if (valid) ob[T + j] = y;   // coalesced 16-float burst per chain
        }
    }
}

extern "C" void kernel_launch(void* const* d_in, const int* in_sizes, int n_in,
                              void* d_out, int out_size, void* d_ws, size_t ws_size,
                              hipStream_t stream) {
    const float* x     = (const float*)d_in[0];
    const float* W_ih  = (const float*)d_in[1];
    const float* W_hh  = (const float*)d_in[2];
    const float* b_ih  = (const float*)d_in[3];
    const float* b_hh  = (const float*)d_in[4];
    const float* W_lin = (const float*)d_in[5];
    const float* b_lin = (const float*)d_in[6];
    float* out = (float*)d_out;

    const int nblocks = (BATCH + 2) / 3;  // 3 chains per 64-thread wave/block
    lstm_fused<<<nblocks, 64, 0, stream>>>(x, W_ih, W_hh, b_ih, b_hh,
                                           W_lin, b_lin, out);
}

// Round 3
// 240.469 us; speedup vs baseline: 1.0015x; 1.0015x over previous
//
#include <hip/hip_runtime.h>

// LSTM B=4096, S=512, INPUT=1, HIDDEN=20 + linear head.
// R5b: identical to R5 (bench infra failed; no kernel signal).  Rationale:
// rebalance to exactly 1024 single-wave blocks (<=1 wave/SIMD chip-wide).
// R3/R4 used 3 chains/wave -> 1366 blocks on 1024 SIMDs: 342 SIMDs carried
// TWO waves (~2x issue/step) and set the wall while 682 SIMDs idled early.
// Now: 4 chains x 16 lanes per wave; lanes j<4 carry a second unit (16+j)
// so 16 lanes cover H=20.  Per-wave issue ~1.6x, but perfectly balanced and
// zero dummy lanes (4096 = 1024*4 exactly; all validity checks gone).
// Kept from R3: fp16 h-ring in LDS (group bases 0,8,16,24 mod 32 banks ->
// conflict-free broadcast b128 row reads), v_dot2_f32_f16 gate dots,
// deferred head per 16-step chunk (all 64 lanes, unmasked).
// Kept from R4: fused-reciprocal activations, 5 exp2 + 2 rcp per unit:
//   c' = (c*(1+I)(1+G) + (1-G)(1+F)) * rcp((1+F)(1+I)(1+G))
//   h  = (1-C) * rcp((1+O)(1+C)),  C = exp2(-2*log2e*c'),  c clamped >= -34.

#define BATCH 4096
#define SLEN  512
#define H     20
#define CHUNK 16
#define LOG2E 1.44269504088896340736f
#define GSTRIDE 200   // words per group LDS region (16 rows * 12 + 8 pad)
#define RSTRIDE 12    // words per h row (10 half2 used + 2 pad)

typedef _Float16 h2 __attribute__((ext_vector_type(2)));

__device__ __forceinline__ float fexp2(float x) { return __builtin_amdgcn_exp2f(x); }
__device__ __forceinline__ float frcp(float x)  { return __builtin_amdgcn_rcpf(x); }
__device__ __forceinline__ h2 bch2(unsigned int u) { return __builtin_bit_cast(h2, u); }

__global__ __launch_bounds__(64, 1) void lstm_fused(
    const float* __restrict__ x,      // [B, S, 1]
    const float* __restrict__ W_ih,   // [80, 1]
    const float* __restrict__ W_hh,   // [80, 20]
    const float* __restrict__ b_ih,   // [80]
    const float* __restrict__ b_hh,   // [80]
    const float* __restrict__ W_lin,  // [1, 20]
    const float* __restrict__ b_lin,  // [1]
    float* __restrict__ out)          // [B, S, 1]
{
    __shared__ __align__(16) unsigned int hw[4 * GSTRIDE];  // h ring, fp16
    __shared__ float xbuf[4][CHUNK];
    _Float16* hh = (_Float16*)hw;

    const int lane = threadIdx.x;       // 0..63
    const int grp  = lane >> 4;         // chain within block, 0..3
    const int j    = lane & 15;         // unit A index, 0..15
    const int jb   = 16 + (j & 3);      // unit B index 16..19 (used if j<4)
    const bool dual = (j < 4);
    const long b = (long)blockIdx.x * 4 + grp;   // 1024*4 = 4096 exact

    const float s1 = -LOG2E;          // sigmoid pre-scale
    const float s2 = -2.0f * LOG2E;   // tanh pre-scale

    // ---- per-lane weights, pre-scaled.  Unit A: 40 VGPRs, unit B: 40. ----
    h2 w2a[4][10], w2b[4][10];
    float bba[4], xwa[4], bbb[4], xwb[4];
#pragma unroll
    for (int g = 0; g < 4; ++g) {
        const float sc = (g == 2) ? s2 : s1;   // torch gate order i,f,g,o
        const int ra = g * H + j;
        const int rb = g * H + jb;
#pragma unroll
        for (int k = 0; k < 10; ++k) {
            h2 ta, tb;
            ta.x = (_Float16)(sc * W_hh[ra * H + 2 * k]);
            ta.y = (_Float16)(sc * W_hh[ra * H + 2 * k + 1]);
            tb.x = (_Float16)(sc * W_hh[rb * H + 2 * k]);
            tb.y = (_Float16)(sc * W_hh[rb * H + 2 * k + 1]);
            w2a[g][k] = ta;
            w2b[g][k] = tb;
        }
        bba[g] = sc * (b_ih[ra] + b_hh[ra]);
        xwa[g] = sc * W_ih[ra];
        bbb[g] = sc * (b_ih[rb] + b_hh[rb]);
        xwb[g] = sc * W_ih[rb];
    }
    h2 wl2[10];
#pragma unroll
    for (int k = 0; k < 10; ++k) {
        h2 t;
        t.x = (_Float16)W_lin[2 * k];
        t.y = (_Float16)W_lin[2 * k + 1];
        wl2[k] = t;
    }
    const float blin = b_lin[0];

    const float* xb = x + b * SLEN;
    float*       ob = out + b * SLEN;

    const int gbase = grp * GSTRIDE;
    // h(-1) = 0 in ring row CHUNK-1
    hh[2 * (gbase + (CHUNK - 1) * RSTRIDE) + j] = (_Float16)0.0f;
    if (dual) hh[2 * (gbase + (CHUNK - 1) * RSTRIDE) + jb] = (_Float16)0.0f;
    float ca = 0.0f, cb = 0.0f;

#pragma unroll 1
    for (int T = 0; T < SLEN; T += CHUNK) {
        xbuf[grp][j] = xb[T + j];   // all 64 lanes; coalesced per chain

#pragma unroll
        for (int i = 0; i < CHUNK; ++i) {
            const int rp = (i + CHUNK - 1) & (CHUNK - 1);
            const int base = gbase + rp * RSTRIDE;
            const float xt = xbuf[grp][i];          // group broadcast
            // h(t-1) row: 20 fp16 = words 0..9 -> b128 + b128 + b64
            const uint4 A = *(const uint4*)&hw[base];
            const uint4 B = *(const uint4*)&hw[base + 4];
            const uint2 C2 = *(const uint2*)&hw[base + 8];
            const unsigned int pw[10] = {A.x, A.y, A.z, A.w,
                                         B.x, B.y, B.z, B.w, C2.x, C2.y};

            // ---- unit A (all lanes) ----
            {
                float a[4];
#pragma unroll
                for (int g = 0; g < 4; ++g) a[g] = fmaf(xt, xwa[g], bba[g]);
#pragma unroll
                for (int k = 0; k < 10; ++k)
#pragma unroll
                    for (int g = 0; g < 4; ++g)
                        a[g] = __builtin_amdgcn_fdot2(bch2(pw[k]), w2a[g][k], a[g], false);
                const float eI = fexp2(a[0]);
                const float eF = fexp2(a[1]);
                const float eG = fexp2(a[2]);
                const float eO = fexp2(a[3]);
                const float pF = 1.0f + eF;
                const float P  = (1.0f + eI) * (1.0f + eG);
                const float num = fmaf(ca, P, (1.0f - eG) * pF);
                ca = fmaxf(num * frcp(pF * P), -34.0f);
                const float eC = fexp2(s2 * ca);
                const float hA = (1.0f - eC) * frcp((1.0f + eO) * (1.0f + eC));
                hh[2 * (gbase + i * RSTRIDE) + j] = (_Float16)hA;
            }
            // ---- unit B (lanes j<4 only) ----
            if (dual) {
                float d[4];
#pragma unroll
                for (int g = 0; g < 4; ++g) d[g] = fmaf(xt, xwb[g], bbb[g]);
#pragma unroll
                for (int k = 0; k < 10; ++k)
#pragma unroll
                    for (int g = 0; g < 4; ++g)
                        d[g] = __builtin_amdgcn_fdot2(bch2(pw[k]), w2b[g][k], d[g], false);
                const float eI = fexp2(d[0]);
                const float eF = fexp2(d[1]);
                const float eG = fexp2(d[2]);
                const float eO = fexp2(d[3]);
                const float pF = 1.0f + eF;
                const float P  = (1.0f + eI) * (1.0f + eG);
                const float num = fmaf(cb, P, (1.0f - eG) * pF);
                cb = fmaxf(num * frcp(pF * P), -34.0f);
                const float eC = fexp2(s2 * cb);
                const float hB = (1.0f - eC) * frcp((1.0f + eO) * (1.0f + eC));
                hh[2 * (gbase + i * RSTRIDE) + jb] = (_Float16)hB;
            }
        }

        // ---- deferred head: each lane reduces one stored row (all 64) ----
        {
            const int rb2 = gbase + j * RSTRIDE;
            const uint4 A = *(const uint4*)&hw[rb2];
            const uint4 B = *(const uint4*)&hw[rb2 + 4];
            const uint2 C2 = *(const uint2*)&hw[rb2 + 8];
            const unsigned int pw[10] = {A.x, A.y, A.z, A.w,
                                         B.x, B.y, B.z, B.w, C2.x, C2.y};
            float y = blin;
#pragma unroll
            for (int k = 0; k < 10; ++k)
                y = __builtin_amdgcn_fdot2(bch2(pw[k]), wl2[k], y, false);
            ob[T + j] = y;   // coalesced 16-float burst per chain
        }
    }
}

extern "C" void kernel_launch(void* const* d_in, const int* in_sizes, int n_in,
                              void* d_out, int out_size, void* d_ws, size_t ws_size,
                              hipStream_t stream) {
    const float* x     = (const float*)d_in[0];
    const float* W_ih  = (const float*)d_in[1];
    const float* W_hh  = (const float*)d_in[2];
    const float* b_ih  = (const float*)d_in[3];
    const float* b_hh  = (const float*)d_in[4];
    const float* W_lin = (const float*)d_in[5];
    const float* b_lin = (const float*)d_in[6];
    float* out = (float*)d_out;

    const int nblocks = BATCH / 4;   // 1024 single-wave blocks: 1 per SIMD
    lstm_fused<<<nblocks, 64, 0, stream>>>(x, W_ih, W_hh, b_ih, b_hh,
                                           W_lin, b_lin, out);
}

// Round 5
// 227.273 us; speedup vs baseline: 1.0597x; 1.0581x over previous
//
#include <hip/hip_runtime.h>

// LSTM B=4096, S=512, INPUT=1, HIDDEN=20 + linear head.
// R6b: R6 with the OOB fix.  R6's bug: grp = lane/20 -> lanes 60..63 got
// grp=3 and wrote past hw[3*GSTRIDE] into xbuf (absmax 0.72).  Now grp is
// clamped to 2: lanes 40..63 are all dummy group 2, writing duplicate
// same-address garbage into the scratch region (benign).
// Design (unchanged from R6): 2048 single-wave blocks x 2 chains = 4096
// exact -> 2 waves per SIMD chip-wide.  R5 showed per-SIMD issue ~600
// cyc/step either way; 1 wave/SIMD leaves ~300 cyc/step of serial-dependence
// stall (LDS h-ring round-trip + dot/trans chains) unhidden.  Two lean
// R3-style waves (20 lanes/chain, one unit/lane, all 4 gates in-lane, no
// dual-unit block) interleave through each other's stalls.
// Kept: fp16 h-ring in LDS (group word bases 0/200/400 -> bank quads
// 0/8/16, broadcast b128 row reads conflict-free), v_dot2_f32_f16 dots,
// fused-reciprocal activations (5 exp2 + 2 rcp per unit):
//   c' = (c*(1+I)(1+G) + (1-G)(1+F)) * rcp((1+F)(1+I)(1+G))
//   h  = (1-C) * rcp((1+O)(1+C)),  C = exp2(-2*log2e*c'),  c clamped >= -34,
// deferred head per 16-step chunk (16 lanes/chain, coalesced store).

#define BATCH 4096
#define SLEN  512
#define H     20
#define CHUNK 16
#define LOG2E 1.44269504088896340736f
#define GSTRIDE 200   // words per group LDS region (16 rows * 12 + 8 pad)
#define RSTRIDE 12    // words per h row (10 half2 used + 2 pad)

typedef _Float16 h2 __attribute__((ext_vector_type(2)));

__device__ __forceinline__ float fexp2(float x) { return __builtin_amdgcn_exp2f(x); }
__device__ __forceinline__ float frcp(float x)  { return __builtin_amdgcn_rcpf(x); }
__device__ __forceinline__ h2 bch2(unsigned int u) { return __builtin_bit_cast(h2, u); }

__global__ __launch_bounds__(64, 2) void lstm_fused(
    const float* __restrict__ x,      // [B, S, 1]
    const float* __restrict__ W_ih,   // [80, 1]
    const float* __restrict__ W_hh,   // [80, 20]
    const float* __restrict__ b_ih,   // [80]
    const float* __restrict__ b_hh,   // [80]
    const float* __restrict__ W_lin,  // [1, 20]
    const float* __restrict__ b_lin,  // [1]
    float* __restrict__ out)          // [B, S, 1]
{
    __shared__ __align__(16) unsigned int hw[3 * GSTRIDE];  // h ring, fp16 (grp2 = scratch)
    __shared__ float xbuf[3][CHUNK];
    _Float16* hh = (_Float16*)hw;

    const int lane = threadIdx.x;       // 0..63
    int grp = lane / H;                 // 0,1 real chains
    if (grp > 2) grp = 2;               // lanes 40..63 all dummy group 2
    const int j    = lane - grp * H;    // 0..19 real; 0..23 for dummy grp
    const bool valid = (grp < 2);
    const long b  = (long)blockIdx.x * 2 + grp;   // 2048*2 = 4096 exact
    const long bc = valid ? b : 0;                // dummies chew on chain 0's x

    const float s1 = -LOG2E;          // sigmoid pre-scale
    const float s2 = -2.0f * LOG2E;   // tanh pre-scale

    // ---- per-lane weights: 4 gate rows x 10 half2 (40 VGPRs), pre-scaled ----
    const int ju = (j < H) ? j : 0;   // clamp dummy lanes' row index
    h2 w2[4][10];
    float bb[4], xw[4];
#pragma unroll
    for (int g = 0; g < 4; ++g) {
        const int row = g * H + ju;
        const float sc = (g == 2) ? s2 : s1;   // torch gate order i,f,g,o
#pragma unroll
        for (int k = 0; k < 10; ++k) {
            h2 t;
            t.x = (_Float16)(sc * W_hh[row * H + 2 * k]);
            t.y = (_Float16)(sc * W_hh[row * H + 2 * k + 1]);
            w2[g][k] = t;
        }
        bb[g] = sc * (b_ih[row] + b_hh[row]);
        xw[g] = sc * W_ih[row];
    }
    h2 wl2[10];
#pragma unroll
    for (int k = 0; k < 10; ++k) {
        h2 t;
        t.x = (_Float16)W_lin[2 * k];
        t.y = (_Float16)W_lin[2 * k + 1];
        wl2[k] = t;
    }
    const float blin = b_lin[0];

    const float* xb = x + bc * SLEN;
    float*       ob = out + bc * SLEN;

    const int gbase = grp * GSTRIDE;   // word bases 0,200,400 -> bank quads 0/8/16
    // h(-1) = 0 in ring row CHUNK-1 (dummy lanes hit scratch region: fine)
    hh[2 * (gbase + (CHUNK - 1) * RSTRIDE) + ju] = (_Float16)0.0f;
    float c = 0.0f;

#pragma unroll 1
    for (int T = 0; T < SLEN; T += CHUNK) {
        if (j < CHUNK) xbuf[grp][j] = xb[T + j];   // coalesced x chunk -> LDS

#pragma unroll
        for (int i = 0; i < CHUNK; ++i) {
            const int rp = (i + CHUNK - 1) & (CHUNK - 1);
            const int base = gbase + rp * RSTRIDE;
            const float xt = xbuf[grp][i];          // group broadcast
            // h(t-1) row: 20 fp16 = words 0..9 -> b128 + b128 + b64
            const uint4 A = *(const uint4*)&hw[base];
            const uint4 B = *(const uint4*)&hw[base + 4];
            const uint2 C2 = *(const uint2*)&hw[base + 8];
            const unsigned int pw[10] = {A.x, A.y, A.z, A.w,
                                         B.x, B.y, B.z, B.w, C2.x, C2.y};
            float a[4];
#pragma unroll
            for (int g = 0; g < 4; ++g) a[g] = fmaf(xt, xw[g], bb[g]);
#pragma unroll
            for (int k = 0; k < 10; ++k)
#pragma unroll
                for (int g = 0; g < 4; ++g)   // 4 independent dep chains
                    a[g] = __builtin_amdgcn_fdot2(bch2(pw[k]), w2[g][k], a[g], false);

            // ---- fused-reciprocal activations: 5 exp2 + 2 rcp ----
            const float eI = fexp2(a[0]);
            const float eF = fexp2(a[1]);
            const float eG = fexp2(a[2]);
            const float eO = fexp2(a[3]);
            const float pF = 1.0f + eF;
            const float P  = (1.0f + eI) * (1.0f + eG);
            const float num = fmaf(c, P, (1.0f - eG) * pF);
            c = fmaxf(num * frcp(pF * P), -34.0f);
            const float eC = fexp2(s2 * c);
            const float hval = (1.0f - eC) * frcp((1.0f + eO) * (1.0f + eC));
            hh[2 * (gbase + i * RSTRIDE) + ju] = (_Float16)hval;  // ds_write_b16
        }

        // ---- deferred head: lanes j<16 reduce one stored row each ----
        if (j < CHUNK) {
            const int rb = gbase + j * RSTRIDE;
            const uint4 A = *(const uint4*)&hw[rb];
            const uint4 B = *(const uint4*)&hw[rb + 4];
            const uint2 C2 = *(const uint2*)&hw[rb + 8];
            const unsigned int pw[10] = {A.x, A.y, A.z, A.w,
                                         B.x, B.y, B.z, B.w, C2.x, C2.y};
            float y = blin;
#pragma unroll
            for (int k = 0; k < 10; ++k)
                y = __builtin_amdgcn_fdot2(bch2(pw[k]), wl2[k], y, false);
            if (valid) ob[T + j] = y;   // coalesced 16-float burst per chain
        }
    }
}

extern "C" void kernel_launch(void* const* d_in, const int* in_sizes, int n_in,
                              void* d_out, int out_size, void* d_ws, size_t ws_size,
                              hipStream_t stream) {
    const float* x     = (const float*)d_in[0];
    const float* W_ih  = (const float*)d_in[1];
    const float* W_hh  = (const float*)d_in[2];
    const float* b_ih  = (const float*)d_in[3];
    const float* b_hh  = (const float*)d_in[4];
    const float* W_lin = (const float*)d_in[5];
    const float* b_lin = (const float*)d_in[6];
    float* out = (float*)d_out;

    const int nblocks = BATCH / 2;   // 2048 single-wave blocks: 2 per SIMD
    lstm_fused<<<nblocks, 64, 0, stream>>>(x, W_ih, W_hh, b_ih, b_hh,
                                           W_lin, b_lin, out);
}